// Round 11
// baseline (420.596 us; speedup 1.0000x reference)
//
#include <hip/hip_runtime.h>

#define CCH 384
#define HH 192
#define WWD 192
#define NIMG 2
#define HWP (HH * WWD)        // 36864 pixels per image
#define PTOT (NIMG * HWP)     // 73728
#define HEADS 12
#define HD 32
#define NWIN 24
#define WINS 576              // windows per image
#define EELEM ((size_t)NIMG * CCH * HWP)   // elems per tensor (28,311,552)
#define WMAT 147456           // 384*384

typedef __attribute__((ext_vector_type(8))) short bh8;            // 8 bf16 (MFMA frag)
typedef __attribute__((ext_vector_type(8))) unsigned short us8;
typedef __attribute__((ext_vector_type(4))) unsigned short us4;
typedef __attribute__((ext_vector_type(4))) float fx4;

__device__ __forceinline__ unsigned short f2bf(float f) {
    unsigned u = __float_as_uint(f);
    u += 0x7fffu + ((u >> 16) & 1u);      // round-to-nearest-even
    return (unsigned short)(u >> 16);
}

__device__ __forceinline__ void gload16(const void* g, void* l) {
    __builtin_amdgcn_global_load_lds(
        (const __attribute__((address_space(1))) void*)g,
        (__attribute__((address_space(3))) void*)l, 16, 0, 0);
}

// ---------------------------------------------------------------------------
// prep (merged): [0,288) pw weights->bf16; [288,329) dw weight transpose;
// [329,521) rel-pos bias expansion Bx[head][tk][tq].
// ---------------------------------------------------------------------------
__global__ __launch_bounds__(256) void prep(
    const float* __restrict__ qp, const float* __restrict__ kp,
    const float* __restrict__ vp, const float* __restrict__ pj,
    const float* __restrict__ qd, const float* __restrict__ kd,
    const float* __restrict__ vd, const float* __restrict__ rpb,
    unsigned short* __restrict__ Wb, float* __restrict__ dwT,
    float* __restrict__ Bx)
{
    int bx = blockIdx.x;
    if (bx < 288) {
        int idx8 = (bx * 256 + threadIdx.x) * 8;
        int which = idx8 / WMAT;
        int loc = idx8 - which * WMAT;
        const float* s = (which == 0) ? qp : (which == 1) ? kp : (which == 2) ? vp : pj;
        float4 v0 = *(const float4*)(s + loc);
        float4 v1 = *(const float4*)(s + loc + 4);
        us8 ov;
        ov[0] = f2bf(v0.x); ov[1] = f2bf(v0.y); ov[2] = f2bf(v0.z); ov[3] = f2bf(v0.w);
        ov[4] = f2bf(v1.x); ov[5] = f2bf(v1.y); ov[6] = f2bf(v1.z); ov[7] = f2bf(v1.w);
        *(us8*)(Wb + idx8) = ov;
    } else if (bx < 329) {
        int idx = (bx - 288) * 256 + threadIdx.x;
        if (idx < 3 * 9 * CCH) {
            int ten = idx / (9 * CCH);
            int rem = idx - ten * (9 * CCH);
            int tap = rem / CCH;
            int c   = rem - tap * CCH;
            const float* s = (ten == 0) ? qd : (ten == 1) ? kd : vd;
            dwT[idx] = s[c * 9 + tap];
        }
    } else {
        int idx = (bx - 329) * 256 + threadIdx.x;   // 192*256 = 49152 exact
        int h  = idx >> 12;
        int tk = (idx >> 6) & 63;
        int tq = idx & 63;
        int dy = (tq >> 3) - (tk >> 3) + 7;
        int dx = (tq & 7) - (tk & 7) + 7;
        Bx[idx] = rpb[(dy * 15 + dx) * HEADS + h];
    }
}

// ---------------------------------------------------------------------------
// FUSED depthwise 3x3 + bias + window-gather transpose (v9 = v7 structure,
// 32-channel chunks for occupancy).
// Block = ONE window (8x8) x 32 channels; grid = 13824 (8 x 1728 XCD swizzle).
// LDS halo: [32 ch][10 rows][12 cols] f32, stride 121 -> 15.5 KB -> 8 blk/CU.
// Thread = channel c x 1 pixel row (8 px), register sliding window (30 reads).
// ---------------------------------------------------------------------------
__global__ __launch_bounds__(256) void dwgather(
    const float* __restrict__ x,
    const float* __restrict__ wt,       // [3][9][384] fp32 transposed dw weights
    const float* __restrict__ qb, const float* __restrict__ kb,
    const float* __restrict__ vb,
    unsigned short* __restrict__ oq, unsigned short* __restrict__ ok,
    unsigned short* __restrict__ ov)
{
    __shared__ float halo[32 * 121];        // 15.5 KB

    // bijective XCD swizzle: 13824 = 8 * 1728
    int bid = blockIdx.x;
    int b = (bid & 7) * 1728 + (bid >> 3);
    int wtx  = b % 24;
    int rest = b / 24;                      // 0..575
    int chv  = rest % 12;
    int nwy  = rest / 12;                   // 0..47
    int wy   = nwy % 24;
    int n    = nwy / 24;

    int h0 = wy * 8, w0 = wtx * 8;
    int tid = threadIdx.x;
    int c   = tid & 31;                     // channel within chunk (lane-varying)
    int pxg = tid >> 5;                     // 0..7 = pixel row
    int cg  = chv * 32 + c;
    int widx = n * WINS + wy * NWIN + wtx;

    const float* xbase = x + (size_t)n * CCH * HWP + (size_t)(chv * 32) * HWP;

    // ---- stage halo: 32ch x 10 rows x 12 cols (cols w0-2 .. w0+9) ----
    for (int j = tid; j < 960; j += 256) {
        int seg = j % 3;
        int t   = j / 3;
        int rr  = t % 10;
        int cc  = t / 10;
        int hr  = h0 - 1 + rr;
        int cb  = w0 - 2 + seg * 4;
        float4 val = make_float4(0.f, 0.f, 0.f, 0.f);
        if (hr >= 0 && hr < HH) {
            const float* p = xbase + (size_t)cc * HWP + (size_t)hr * WWD;
            if (cb >= 0 && cb + 4 <= WWD) {
                val = *(const float4*)(p + cb);
            } else {
                if (cb + 0 >= 0 && cb + 0 < WWD) val.x = p[cb + 0];
                if (cb + 1 >= 0 && cb + 1 < WWD) val.y = p[cb + 1];
                if (cb + 2 >= 0 && cb + 2 < WWD) val.z = p[cb + 2];
                if (cb + 3 >= 0 && cb + 3 < WWD) val.w = p[cb + 3];
            }
        }
        int hb = cc * 121 + rr * 12 + seg * 4;
        halo[hb + 0] = val.x;
        halo[hb + 1] = val.y;
        halo[hb + 2] = val.z;
        halo[hb + 3] = val.w;
    }

    // ---- per-lane weights, coalesced ([tap][384] layout) ----
    float wq[9], wk[9], wv[9];
#pragma unroll
    for (int t = 0; t < 9; ++t) {
        wq[t] = wt[t * CCH + cg];
        wk[t] = wt[9 * CCH + t * CCH + cg];
        wv[t] = wt[18 * CCH + t * CCH + cg];
    }
    float bqv = qb[cg], bkv = kb[cg], bvv = vb[cg];

    __syncthreads();

    // ---- register sliding window: rows pxg..pxg+2, cols 1..10 ----
    const int hbase = c * 121 + pxg * 12;
    float r0[10], r1[10], r2[10];
#pragma unroll
    for (int cc = 0; cc < 10; ++cc) r0[cc] = halo[hbase + cc + 1];
#pragma unroll
    for (int cc = 0; cc < 10; ++cc) r1[cc] = halo[hbase + 12 + cc + 1];
#pragma unroll
    for (int cc = 0; cc < 10; ++cc) r2[cc] = halo[hbase + 24 + cc + 1];

    size_t ob0 = ((size_t)widx * 64 + pxg * 8) * CCH + cg;

#pragma unroll
    for (int pc = 0; pc < 8; ++pc) {
        float sq = 0.f, sk = 0.f, sv = 0.f;
#pragma unroll
        for (int dc = 0; dc < 3; ++dc) {
            float x0 = r0[pc + dc], x1 = r1[pc + dc], x2 = r2[pc + dc];
            sq = fmaf(x0, wq[dc], sq);     sk = fmaf(x0, wk[dc], sk);     sv = fmaf(x0, wv[dc], sv);
            sq = fmaf(x1, wq[3 + dc], sq); sk = fmaf(x1, wk[3 + dc], sk); sv = fmaf(x1, wv[3 + dc], sv);
            sq = fmaf(x2, wq[6 + dc], sq); sk = fmaf(x2, wk[6 + dc], sk); sv = fmaf(x2, wv[6 + dc], sv);
        }
        size_t o = ob0 + (size_t)pc * CCH;
        oq[o] = f2bf(sq + bqv);
        ok[o] = f2bf(sk + bkv);
        ov[o] = f2bf(sv + bvv);
    }
}

// ---------------------------------------------------------------------------
// MERGED q/k/v bf16 MFMA GEMM: grid (576, 3, 3); blockIdx.z picks tensor.
// z=0: q (orient1, *scale), z=1: k (orient1), z=2: v (orient2, V^T out).
// Double-buffered global_load_lds, 1 barrier/K-step, coalesced LDS epilogue.
// ---------------------------------------------------------------------------
__global__ __launch_bounds__(256) void qkv_gemm(
    const unsigned short* __restrict__ tr0, const unsigned short* __restrict__ tr1,
    const unsigned short* __restrict__ tr2, const unsigned short* __restrict__ Wball,
    const float* __restrict__ qpb, const float* __restrict__ kpb,
    const float* __restrict__ vpb, float scale,
    unsigned short* __restrict__ qo, unsigned short* __restrict__ ko,
    unsigned short* __restrict__ vo)
{
    __shared__ __align__(16) char smem[33792];   // staging (32KB) U epilogue T16
    typedef unsigned short (*tile3)[128][32];
    tile3 Wt = (tile3)smem;
    tile3 Yt = (tile3)(smem + 16384);
    typedef unsigned short (*tep_t)[132];
    tep_t T16 = (tep_t)smem;

    int z = blockIdx.z;
    const unsigned short* Y  = (z == 0) ? tr0 : (z == 1) ? tr1 : tr2;
    const unsigned short* Wb = Wball + (size_t)z * WMAT;
    const float* bias        = (z == 0) ? qpb : (z == 1) ? kpb : vpb;
    float sc                 = (z == 0) ? scale : 1.0f;
    unsigned short* outb     = (z == 0) ? qo : (z == 1) ? ko : vo;
    bool vmode = (z == 2);

    int tid = threadIdx.x;
    int pp0 = blockIdx.x * 128;
    int cm0 = blockIdx.y * 128;
    int lid = tid & 63, wid = tid >> 6;
    int wr = wid >> 1, wc = wid & 1;
    int li = lid & 15, g = lid >> 4;

    int srow = (lid >> 2);               // 0..15 within 16-row group
    int scol = (lid & 3) * 8;            // 0,8,16,24 (u16)

    fx4 acc[4][4];
#pragma unroll
    for (int i = 0; i < 4; ++i)
#pragma unroll
        for (int j = 0; j < 4; ++j) acc[i][j] = (fx4){0.f, 0.f, 0.f, 0.f};

    tile3 A3 = vmode ? Yt : Wt;          // block-uniform select
    tile3 B3 = vmode ? Wt : Yt;

    const unsigned short* Wg0 = Wb + (size_t)(cm0 + wid * 32 + srow) * CCH + scol;
    const unsigned short* Yg0 = Y  + (size_t)(pp0 + wid * 32 + srow) * CCH + scol;

#pragma unroll
    for (int qi = 0; qi < 2; ++qi) {
        gload16(Wg0 + (size_t)qi * 16 * CCH, &Wt[0][wid * 32 + qi * 16][0]);
        gload16(Yg0 + (size_t)qi * 16 * CCH, &Yt[0][wid * 32 + qi * 16][0]);
    }
    __syncthreads();

    for (int kt = 0; kt < 12; ++kt) {
        int cur = kt & 1;
        if (kt < 11) {
            int k1 = (kt + 1) * 32;
#pragma unroll
            for (int qi = 0; qi < 2; ++qi) {
                gload16(Wg0 + (size_t)qi * 16 * CCH + k1, &Wt[cur ^ 1][wid * 32 + qi * 16][0]);
                gload16(Yg0 + (size_t)qi * 16 * CCH + k1, &Yt[cur ^ 1][wid * 32 + qi * 16][0]);
            }
        }

        bh8 a[4], b[4];
#pragma unroll
        for (int mf = 0; mf < 4; ++mf)
            a[mf] = *(const bh8*)&A3[cur][wr * 64 + mf * 16 + li][g * 8];
#pragma unroll
        for (int nf = 0; nf < 4; ++nf)
            b[nf] = *(const bh8*)&B3[cur][wc * 64 + nf * 16 + li][g * 8];
#pragma unroll
        for (int mf = 0; mf < 4; ++mf)
#pragma unroll
            for (int nf = 0; nf < 4; ++nf)
                acc[mf][nf] = __builtin_amdgcn_mfma_f32_16x16x32_bf16(
                    a[mf], b[nf], acc[mf][nf], 0, 0, 0);

        __syncthreads();
    }

    if (!vmode) {
        // D rows = c (A=W), cols = p. T16[p_local][c_local]; out [p][c].
#pragma unroll
        for (int mf = 0; mf < 4; ++mf) {
            int cl = wr * 64 + mf * 16 + g * 4;
            float4 bv = *(const float4*)&bias[cm0 + cl];
#pragma unroll
            for (int nf = 0; nf < 4; ++nf) {
                int pl = wc * 64 + nf * 16 + li;
                us4 o;
                o[0] = f2bf((acc[mf][nf][0] + bv.x) * sc);
                o[1] = f2bf((acc[mf][nf][1] + bv.y) * sc);
                o[2] = f2bf((acc[mf][nf][2] + bv.z) * sc);
                o[3] = f2bf((acc[mf][nf][3] + bv.w) * sc);
                *(us4*)&T16[pl][cl] = o;
            }
        }
        __syncthreads();
#pragma unroll
        for (int it = 0; it < 8; ++it) {
            int row = it * 16 + wid * 4 + (lid >> 4);
            int col = (lid & 15) * 8;
            us8 vv = *(const us8*)&T16[row][col];
            *(us8*)(outb + (size_t)(pp0 + row) * CCH + cm0 + col) = vv;
        }
    } else {
        // D rows = p (A=Y), cols = c. T16[c_local][p_local]; out [n][c][p_l].
#pragma unroll
        for (int nf = 0; nf < 4; ++nf) {
            int cl = wc * 64 + nf * 16 + li;
            float bv = bias[cm0 + cl];
#pragma unroll
            for (int mf = 0; mf < 4; ++mf) {
                int pl = wr * 64 + mf * 16 + g * 4;
                us4 o;
                o[0] = f2bf(acc[mf][nf][0] + bv);
                o[1] = f2bf(acc[mf][nf][1] + bv);
                o[2] = f2bf(acc[mf][nf][2] + bv);
                o[3] = f2bf(acc[mf][nf][3] + bv);
                *(us4*)&T16[cl][pl] = o;
            }
        }
        __syncthreads();
        int n = pp0 / HWP;
        int pl0 = pp0 - n * HWP;
#pragma unroll
        for (int it = 0; it < 8; ++it) {
            int row = it * 16 + wid * 4 + (lid >> 4);   // c_local
            int col = (lid & 15) * 8;                   // p_local
            us8 vv = *(const us8*)&T16[row][col];
            *(us8*)(outb + (size_t)(n * CCH + cm0 + row) * HWP + pl0 + col) = vv;
        }
    }
}

// ---------------------------------------------------------------------------
// proj GEMM: fp32 std-layout output with inverse window gather (direct stores).
// ---------------------------------------------------------------------------
__global__ __launch_bounds__(256) void proj_gemm(
    const unsigned short* __restrict__ Y, const unsigned short* __restrict__ Wb,
    const float* __restrict__ bias, float* __restrict__ outf)
{
    __shared__ unsigned short Wt[2][128][32];
    __shared__ unsigned short Yt[2][128][32];

    int tid = threadIdx.x;
    int pp0 = blockIdx.x * 128;
    int cm0 = blockIdx.y * 128;
    int lid = tid & 63, wid = tid >> 6;
    int wr = wid >> 1, wc = wid & 1;
    int li = lid & 15, g = lid >> 4;

    int srow = (lid >> 2);
    int scol = (lid & 3) * 8;

    fx4 acc[4][4];
#pragma unroll
    for (int i = 0; i < 4; ++i)
#pragma unroll
        for (int j = 0; j < 4; ++j) acc[i][j] = (fx4){0.f, 0.f, 0.f, 0.f};

    const unsigned short* Wg0 = Wb + (size_t)(cm0 + wid * 32 + srow) * CCH + scol;
    const unsigned short* Yg0 = Y  + (size_t)(pp0 + wid * 32 + srow) * CCH + scol;

#pragma unroll
    for (int qi = 0; qi < 2; ++qi) {
        gload16(Wg0 + (size_t)qi * 16 * CCH, &Wt[0][wid * 32 + qi * 16][0]);
        gload16(Yg0 + (size_t)qi * 16 * CCH, &Yt[0][wid * 32 + qi * 16][0]);
    }
    __syncthreads();

    for (int kt = 0; kt < 12; ++kt) {
        int cur = kt & 1;
        if (kt < 11) {
            int k1 = (kt + 1) * 32;
#pragma unroll
            for (int qi = 0; qi < 2; ++qi) {
                gload16(Wg0 + (size_t)qi * 16 * CCH + k1, &Wt[cur ^ 1][wid * 32 + qi * 16][0]);
                gload16(Yg0 + (size_t)qi * 16 * CCH + k1, &Yt[cur ^ 1][wid * 32 + qi * 16][0]);
            }
        }

        bh8 a[4], b[4];
#pragma unroll
        for (int mf = 0; mf < 4; ++mf)
            a[mf] = *(const bh8*)&Wt[cur][wr * 64 + mf * 16 + li][g * 8];
#pragma unroll
        for (int nf = 0; nf < 4; ++nf)
            b[nf] = *(const bh8*)&Yt[cur][wc * 64 + nf * 16 + li][g * 8];
#pragma unroll
        for (int mf = 0; mf < 4; ++mf)
#pragma unroll
            for (int nf = 0; nf < 4; ++nf)
                acc[mf][nf] = __builtin_amdgcn_mfma_f32_16x16x32_bf16(
                    a[mf], b[nf], acc[mf][nf], 0, 0, 0);

        __syncthreads();
    }

    // D rows = c, cols = p (lane). fp32 std layout, un-gather windows.
#pragma unroll
    for (int mf = 0; mf < 4; ++mf) {
        int c = cm0 + wr * 64 + mf * 16 + g * 4;
#pragma unroll
        for (int nf = 0; nf < 4; ++nf) {
            int p = pp0 + wc * 64 + nf * 16 + li;
            int n = p / HWP;
            int rem = p - n * HWP;
            int win = rem >> 6, t = rem & 63;
            int h = (win / NWIN) * 8 + (t >> 3);
            int w = (win % NWIN) * 8 + (t & 7);
            float* op = outf + (size_t)n * CCH * HWP + (size_t)h * WWD + w;
#pragma unroll
            for (int r = 0; r < 4; ++r)
                op[(size_t)(c + r) * HWP] = acc[mf][nf][r] + bias[c + r];
        }
    }
}

// ---------------------------------------------------------------------------
// MFMA window attention. block = one window (64 tokens); 4 waves x 3 heads.
// q,k: bf16 [p_wg][384]; v: bf16 [n][c][p_local] (= V^T); out: bf16 [p_wg][384].
// bias from precomputed Bx[head][tk][tq] f32 (L2-resident); no barriers.
// ---------------------------------------------------------------------------
__global__ __launch_bounds__(256) void attn(
    const unsigned short* __restrict__ q, const unsigned short* __restrict__ k,
    const unsigned short* __restrict__ v, const float* __restrict__ Bx,
    unsigned short* __restrict__ o)
{
    __shared__ unsigned short Pl[4][64][72];

    int tid = threadIdx.x, lid = tid & 63, wid = tid >> 6;
    int wl = blockIdx.x;
    int n = wl / WINS, winl = wl - n * WINS;
    int li = lid & 15, g = lid >> 4;

    const fx4 z = (fx4){0.f, 0.f, 0.f, 0.f};

    for (int hq = wid; hq < HEADS; hq += 4) {
        const unsigned short* qp = q + (size_t)(wl * 64) * CCH + hq * HD + g * 8;
        const unsigned short* kp = k + (size_t)(wl * 64) * CCH + hq * HD + g * 8;
        bh8 aq[4], bk[4];
#pragma unroll
        for (int mf = 0; mf < 4; ++mf)
            aq[mf] = *(const bh8*)(qp + (size_t)(mf * 16 + li) * CCH);
#pragma unroll
        for (int nf = 0; nf < 4; ++nf)
            bk[nf] = *(const bh8*)(kp + (size_t)(nf * 16 + li) * CCH);

        fx4 s[4][4];
#pragma unroll
        for (int mf = 0; mf < 4; ++mf)
#pragma unroll
            for (int nf = 0; nf < 4; ++nf)
                s[mf][nf] = __builtin_amdgcn_mfma_f32_16x16x32_bf16(aq[mf], bk[nf], z, 0, 0, 0);

        // bias: vector loads from expanded table (tq = mf*16+g*4+r, tk = nf*16+li)
#pragma unroll
        for (int mf = 0; mf < 4; ++mf)
#pragma unroll
            for (int nf = 0; nf < 4; ++nf) {
                fx4 bv = *(const fx4*)&Bx[((size_t)hq * 64 + nf * 16 + li) * 64
                                          + mf * 16 + g * 4];
                s[mf][nf] += bv;
            }

        // softmax across tk (lane group of 16 shares a row set)
        float inv_[4][4];
#pragma unroll
        for (int mf = 0; mf < 4; ++mf)
#pragma unroll
            for (int r = 0; r < 4; ++r) {
                float m = s[mf][0][r];
#pragma unroll
                for (int nf = 1; nf < 4; ++nf) m = fmaxf(m, s[mf][nf][r]);
                m = fmaxf(m, __shfl_xor(m, 1));
                m = fmaxf(m, __shfl_xor(m, 2));
                m = fmaxf(m, __shfl_xor(m, 4));
                m = fmaxf(m, __shfl_xor(m, 8));
                float sum = 0.f;
#pragma unroll
                for (int nf = 0; nf < 4; ++nf) {
                    float e = __expf(s[mf][nf][r] - m);
                    s[mf][nf][r] = e;
                    sum += e;
                }
                sum += __shfl_xor(sum, 1);
                sum += __shfl_xor(sum, 2);
                sum += __shfl_xor(sum, 4);
                sum += __shfl_xor(sum, 8);
                inv_[mf][r] = 1.f / sum;
            }

        // P -> per-wave LDS, bf16, row-major [tq][tk]
#pragma unroll
        for (int mf = 0; mf < 4; ++mf)
#pragma unroll
            for (int nf = 0; nf < 4; ++nf)
#pragma unroll
                for (int r = 0; r < 4; ++r)
                    Pl[wid][mf * 16 + g * 4 + r][nf * 16 + li] =
                        f2bf(s[mf][nf][r] * inv_[mf][r]);

        // O^T = V^T x P^T : D[d][tq]
        fx4 o2[2][4];
#pragma unroll
        for (int m2 = 0; m2 < 2; ++m2)
#pragma unroll
            for (int nf = 0; nf < 4; ++nf) o2[m2][nf] = z;
#pragma unroll
        for (int ks = 0; ks < 2; ++ks) {
            bh8 av[2], bp[4];
#pragma unroll
            for (int m2 = 0; m2 < 2; ++m2)
                av[m2] = *(const bh8*)(v + (size_t)(n * CCH + hq * HD + m2 * 16 + li) * HWP
                                         + winl * 64 + ks * 32 + g * 8);
#pragma unroll
            for (int nf = 0; nf < 4; ++nf)
                bp[nf] = *(const bh8*)&Pl[wid][nf * 16 + li][ks * 32 + g * 8];
#pragma unroll
            for (int m2 = 0; m2 < 2; ++m2)
#pragma unroll
                for (int nf = 0; nf < 4; ++nf)
                    o2[m2][nf] = __builtin_amdgcn_mfma_f32_16x16x32_bf16(
                        av[m2], bp[nf], o2[m2][nf], 0, 0, 0);
        }
#pragma unroll
        for (int nf = 0; nf < 4; ++nf) {
            int tq = nf * 16 + li;
#pragma unroll
            for (int m2 = 0; m2 < 2; ++m2) {
                int d = hq * HD + m2 * 16 + g * 4;
                us4 ov;
                ov[0] = f2bf(o2[m2][nf][0]);
                ov[1] = f2bf(o2[m2][nf][1]);
                ov[2] = f2bf(o2[m2][nf][2]);
                ov[3] = f2bf(o2[m2][nf][3]);
                *(us4*)(o + (size_t)(wl * 64 + tq) * CCH + d) = ov;
            }
        }
    }
}

// ---------------------------------------------------------------------------
extern "C" void kernel_launch(void* const* d_in, const int* in_sizes, int n_in,
                              void* d_out, int out_size, void* d_ws, size_t ws_size,
                              hipStream_t stream) {
    const float* vid  = (const float*)d_in[0];
    const float* qd_w = (const float*)d_in[1];
    const float* qd_b = (const float*)d_in[2];
    const float* qp_w = (const float*)d_in[3];
    const float* qp_b = (const float*)d_in[4];
    const float* kd_w = (const float*)d_in[5];
    const float* kd_b = (const float*)d_in[6];
    const float* kp_w = (const float*)d_in[7];
    const float* kp_b = (const float*)d_in[8];
    const float* vd_w = (const float*)d_in[9];
    const float* vd_b = (const float*)d_in[10];
    const float* vp_w = (const float*)d_in[11];
    const float* vp_b = (const float*)d_in[12];
    const float* rpb  = (const float*)d_in[13];
    const float* pj_w = (const float*)d_in[14];
    const float* pj_b = (const float*)d_in[15];

    unsigned short* ws16 = (unsigned short*)d_ws;
    unsigned short* tr0 = ws16 + 3 * EELEM;     // [p_wg][c] bf16 (q,k,v pre-GEMM)
    unsigned short* tr1 = ws16 + 4 * EELEM;
    unsigned short* tr2 = ws16 + 5 * EELEM;
    unsigned short* Wb  = ws16 + 6 * EELEM;     // 4 x 147456 bf16
    float* dwT          = (float*)(Wb + 4 * WMAT);      // [3][9][384] fp32
    float* Bx           = dwT + 3 * 9 * CCH;            // [12][64][64] fp32
    unsigned short* qb  = ws16;                 // post-GEMM q,k,v
    unsigned short* kb  = ws16 + EELEM;
    unsigned short* vb  = ws16 + 2 * EELEM;
    unsigned short* ob  = tr0;                  // attn out reuses tr region

    prep<<<521, 256, 0, stream>>>(qp_w, kp_w, vp_w, pj_w,
                                  qd_w, kd_w, vd_w, rpb, Wb, dwT, Bx);
    dwgather<<<NIMG * WINS * 12, 256, 0, stream>>>(
        vid, dwT, qd_b, kd_b, vd_b, tr0, tr1, tr2);

    const float scale = 0.17677669529663687f;   // 32^-0.5 folded into q
    qkv_gemm<<<dim3(PTOT / 128, 3, 3), 256, 0, stream>>>(
        tr0, tr1, tr2, Wb, qp_b, kp_b, vp_b, scale, qb, kb, vb);

    attn<<<NIMG * WINS, 256, 0, stream>>>(qb, kb, vb, Bx, ob);

    proj_gemm<<<dim3(PTOT / 128, 3), 256, 0, stream>>>(
        ob, Wb + 3 * WMAT, pj_b, (float*)d_out);
}

// Round 12
// 395.175 us; speedup vs baseline: 1.0643x; 1.0643x over previous
//
#include <hip/hip_runtime.h>

#define CCH 384
#define HH 192
#define WWD 192
#define NIMG 2
#define HWP (HH * WWD)        // 36864 pixels per image
#define PTOT (NIMG * HWP)     // 73728
#define HEADS 12
#define HD 32
#define NWIN 24
#define WINS 576              // windows per image
#define EELEM ((size_t)NIMG * CCH * HWP)   // elems per tensor (28,311,552)
#define WMAT 147456           // 384*384

typedef __attribute__((ext_vector_type(8))) short bh8;            // 8 bf16 (MFMA frag)
typedef __attribute__((ext_vector_type(8))) unsigned short us8;
typedef __attribute__((ext_vector_type(4))) unsigned short us4;
typedef __attribute__((ext_vector_type(4))) float fx4;

__device__ __forceinline__ unsigned short f2bf(float f) {
    unsigned u = __float_as_uint(f);
    u += 0x7fffu + ((u >> 16) & 1u);      // round-to-nearest-even
    return (unsigned short)(u >> 16);
}

__device__ __forceinline__ void gload16(const void* g, void* l) {
    __builtin_amdgcn_global_load_lds(
        (const __attribute__((address_space(1))) void*)g,
        (__attribute__((address_space(3))) void*)l, 16, 0, 0);
}

// ---------------------------------------------------------------------------
// prep (merged): [0,288) pw weights->bf16; [288,329) dw weight transpose;
// [329,521) rel-pos bias expansion Bx[head][tk][tq].
// ---------------------------------------------------------------------------
__global__ __launch_bounds__(256) void prep(
    const float* __restrict__ qp, const float* __restrict__ kp,
    const float* __restrict__ vp, const float* __restrict__ pj,
    const float* __restrict__ qd, const float* __restrict__ kd,
    const float* __restrict__ vd, const float* __restrict__ rpb,
    unsigned short* __restrict__ Wb, float* __restrict__ dwT,
    float* __restrict__ Bx)
{
    int bx = blockIdx.x;
    if (bx < 288) {
        int idx8 = (bx * 256 + threadIdx.x) * 8;
        int which = idx8 / WMAT;
        int loc = idx8 - which * WMAT;
        const float* s = (which == 0) ? qp : (which == 1) ? kp : (which == 2) ? vp : pj;
        float4 v0 = *(const float4*)(s + loc);
        float4 v1 = *(const float4*)(s + loc + 4);
        us8 ov;
        ov[0] = f2bf(v0.x); ov[1] = f2bf(v0.y); ov[2] = f2bf(v0.z); ov[3] = f2bf(v0.w);
        ov[4] = f2bf(v1.x); ov[5] = f2bf(v1.y); ov[6] = f2bf(v1.z); ov[7] = f2bf(v1.w);
        *(us8*)(Wb + idx8) = ov;
    } else if (bx < 329) {
        int idx = (bx - 288) * 256 + threadIdx.x;
        if (idx < 3 * 9 * CCH) {
            int ten = idx / (9 * CCH);
            int rem = idx - ten * (9 * CCH);
            int tap = rem / CCH;
            int c   = rem - tap * CCH;
            const float* s = (ten == 0) ? qd : (ten == 1) ? kd : vd;
            dwT[idx] = s[c * 9 + tap];
        }
    } else {
        int idx = (bx - 329) * 256 + threadIdx.x;   // 192*256 = 49152 exact
        int h  = idx >> 12;
        int tk = (idx >> 6) & 63;
        int tq = idx & 63;
        int dy = (tq >> 3) - (tk >> 3) + 7;
        int dx = (tq & 7) - (tk & 7) + 7;
        Bx[idx] = rpb[(dy * 15 + dx) * HEADS + h];
    }
}

// ---------------------------------------------------------------------------
// FUSED depthwise 3x3 + bias + window-gather transpose (v7, proven 125us).
// Block = ONE window (8x8) x 64 channels; grid = 6912 (8 x 864 XCD swizzle).
// LDS halo: [64 ch][10 rows][12 cols] f32, stride 121 (odd -> 2-way free).
// Thread = channel c x 2 pixel rows (16 px), register sliding window.
// ---------------------------------------------------------------------------
__global__ __launch_bounds__(256) void dwgather(
    const float* __restrict__ x,
    const float* __restrict__ wt,       // [3][9][384] fp32 transposed dw weights
    const float* __restrict__ qb, const float* __restrict__ kb,
    const float* __restrict__ vb,
    unsigned short* __restrict__ oq, unsigned short* __restrict__ ok,
    unsigned short* __restrict__ ov)
{
    __shared__ float halo[64 * 121];        // 30.25 KB

    // bijective XCD swizzle: 6912 = 8 * 864
    int bid = blockIdx.x;
    int b = (bid & 7) * 864 + (bid >> 3);
    int wtx  = b % 24;
    int strip = b / 24;                     // 0..287
    int chv  = strip % 6;
    int nwy  = strip / 6;                   // 0..47
    int wy   = nwy % 24;
    int n    = nwy / 24;

    int h0 = wy * 8, w0 = wtx * 8;
    int tid = threadIdx.x;
    int c   = tid & 63;                     // channel within chunk (lane-varying)
    int pxg = tid >> 6;                     // wave id: owns pixel rows 2pxg,2pxg+1
    int cg  = chv * 64 + c;
    int widx = n * WINS + wy * NWIN + wtx;

    const float* xbase = x + (size_t)n * CCH * HWP + (size_t)(chv * 64) * HWP;

    // ---- stage halo: 64ch x 10 rows x 12 cols (cols w0-2 .. w0+9) ----
    for (int j = tid; j < 1920; j += 256) {
        int seg = j % 3;
        int t   = j / 3;
        int rr  = t % 10;
        int cc  = t / 10;
        int hr  = h0 - 1 + rr;
        int cb  = w0 - 2 + seg * 4;
        float4 val = make_float4(0.f, 0.f, 0.f, 0.f);
        if (hr >= 0 && hr < HH) {
            const float* p = xbase + (size_t)cc * HWP + (size_t)hr * WWD;
            if (cb >= 0 && cb + 4 <= WWD) {
                val = *(const float4*)(p + cb);
            } else {
                if (cb + 0 >= 0 && cb + 0 < WWD) val.x = p[cb + 0];
                if (cb + 1 >= 0 && cb + 1 < WWD) val.y = p[cb + 1];
                if (cb + 2 >= 0 && cb + 2 < WWD) val.z = p[cb + 2];
                if (cb + 3 >= 0 && cb + 3 < WWD) val.w = p[cb + 3];
            }
        }
        int hb = cc * 121 + rr * 12 + seg * 4;
        halo[hb + 0] = val.x;
        halo[hb + 1] = val.y;
        halo[hb + 2] = val.z;
        halo[hb + 3] = val.w;
    }

    // ---- per-lane weights, coalesced ([tap][384] layout) ----
    float wq[9], wk[9], wv[9];
#pragma unroll
    for (int t = 0; t < 9; ++t) {
        wq[t] = wt[t * CCH + cg];
        wk[t] = wt[9 * CCH + t * CCH + cg];
        wv[t] = wt[18 * CCH + t * CCH + cg];
    }
    float bqv = qb[cg], bkv = kb[cg], bvv = vb[cg];

    __syncthreads();

    // ---- register sliding window: rows 2pxg..2pxg+3, cols 1..10 ----
    const int hbase = c * 121 + (2 * pxg) * 12;
    float r0[10], r1[10], r2[10];
#pragma unroll
    for (int cc = 0; cc < 10; ++cc) r0[cc] = halo[hbase + cc + 1];
#pragma unroll
    for (int cc = 0; cc < 10; ++cc) r1[cc] = halo[hbase + 12 + cc + 1];
#pragma unroll
    for (int cc = 0; cc < 10; ++cc) r2[cc] = halo[hbase + 24 + cc + 1];

    size_t ob0 = ((size_t)widx * 64 + pxg * 16) * CCH + cg;

    // pixel row 0: taps r0,r1,r2
#pragma unroll
    for (int pc = 0; pc < 8; ++pc) {
        float sq = 0.f, sk = 0.f, sv = 0.f;
#pragma unroll
        for (int dc = 0; dc < 3; ++dc) {
            float x0 = r0[pc + dc], x1 = r1[pc + dc], x2 = r2[pc + dc];
            sq = fmaf(x0, wq[dc], sq);     sk = fmaf(x0, wk[dc], sk);     sv = fmaf(x0, wv[dc], sv);
            sq = fmaf(x1, wq[3 + dc], sq); sk = fmaf(x1, wk[3 + dc], sk); sv = fmaf(x1, wv[3 + dc], sv);
            sq = fmaf(x2, wq[6 + dc], sq); sk = fmaf(x2, wk[6 + dc], sk); sv = fmaf(x2, wv[6 + dc], sv);
        }
        size_t o = ob0 + (size_t)pc * CCH;
        oq[o] = f2bf(sq + bqv);
        ok[o] = f2bf(sk + bkv);
        ov[o] = f2bf(sv + bvv);
    }

    // rotate: r0 <- row 2pxg+3
#pragma unroll
    for (int cc = 0; cc < 10; ++cc) r0[cc] = halo[hbase + 36 + cc + 1];

    // pixel row 1: taps r1,r2,r0
#pragma unroll
    for (int pc = 0; pc < 8; ++pc) {
        float sq = 0.f, sk = 0.f, sv = 0.f;
#pragma unroll
        for (int dc = 0; dc < 3; ++dc) {
            float x0 = r1[pc + dc], x1 = r2[pc + dc], x2 = r0[pc + dc];
            sq = fmaf(x0, wq[dc], sq);     sk = fmaf(x0, wk[dc], sk);     sv = fmaf(x0, wv[dc], sv);
            sq = fmaf(x1, wq[3 + dc], sq); sk = fmaf(x1, wk[3 + dc], sk); sv = fmaf(x1, wv[3 + dc], sv);
            sq = fmaf(x2, wq[6 + dc], sq); sk = fmaf(x2, wk[6 + dc], sk); sv = fmaf(x2, wv[6 + dc], sv);
        }
        size_t o = ob0 + (size_t)(8 + pc) * CCH;
        oq[o] = f2bf(sq + bqv);
        ok[o] = f2bf(sk + bkv);
        ov[o] = f2bf(sv + bvv);
    }
}

// ---------------------------------------------------------------------------
// MERGED q/k/v bf16 MFMA GEMM. 1-D grid 5184 = 8 XCD x 648; bijective decode
// puts the 3 c-tiles of one p-tile adjacent on one XCD (Y panel L2-reuse).
// LDS st-swizzle (slot ^= (row>>1)&3, both sides) kills 8-way ds_read
// conflicts; gload_lds dest stays linear, global SOURCE is pre-swizzled.
// z=0: q (*scale), z=1: k, z=2: v (V^T out). Coalesced LDS epilogue.
// ---------------------------------------------------------------------------
__global__ __launch_bounds__(256) void qkv_gemm(
    const unsigned short* __restrict__ tr0, const unsigned short* __restrict__ tr1,
    const unsigned short* __restrict__ tr2, const unsigned short* __restrict__ Wball,
    const float* __restrict__ qpb, const float* __restrict__ kpb,
    const float* __restrict__ vpb, float scale,
    unsigned short* __restrict__ qo, unsigned short* __restrict__ ko,
    unsigned short* __restrict__ vo)
{
    __shared__ __align__(16) char smem[33792];   // staging (32KB) U epilogue T16
    typedef unsigned short (*tile3)[128][32];
    tile3 Wt = (tile3)smem;
    tile3 Yt = (tile3)(smem + 16384);
    typedef unsigned short (*tep_t)[132];
    tep_t T16 = (tep_t)smem;

    // decode: O = tensor-major, then p-tile, c-tile innermost (L2 reuse of Y)
    int bL = blockIdx.x;
    int O  = (bL & 7) * 648 + (bL >> 3);
    int z  = O / 1728;
    int rem = O - z * 1728;
    int py = rem / 3;
    int cx = rem - py * 3;
    int pp0 = py * 128, cm0 = cx * 128;

    const unsigned short* Y  = (z == 0) ? tr0 : (z == 1) ? tr1 : tr2;
    const unsigned short* Wb = Wball + (size_t)z * WMAT;
    const float* bias        = (z == 0) ? qpb : (z == 1) ? kpb : vpb;
    float sc                 = (z == 0) ? scale : 1.0f;
    unsigned short* outb     = (z == 0) ? qo : (z == 1) ? ko : vo;
    bool vmode = (z == 2);

    int tid = threadIdx.x;
    int lid = tid & 63, wid = tid >> 6;
    int wr = wid >> 1, wc = wid & 1;
    int li = lid & 15, g = lid >> 4;

    // staging: srow 0..15 in 16-row group; SOURCE slot pre-swizzled
    int srow = (lid >> 2);
    int scol = (((lid & 3) ^ ((srow >> 1) & 3))) * 8;
    // read-side swizzled k-slot (row base multiples of 16 -> depends on li only)
    int gsw = (g ^ ((li >> 1) & 3)) * 8;

    fx4 acc[4][4];
#pragma unroll
    for (int i = 0; i < 4; ++i)
#pragma unroll
        for (int j = 0; j < 4; ++j) acc[i][j] = (fx4){0.f, 0.f, 0.f, 0.f};

    tile3 A3 = vmode ? Yt : Wt;          // block-uniform select
    tile3 B3 = vmode ? Wt : Yt;

    const unsigned short* Wg0 = Wb + (size_t)(cm0 + wid * 32 + srow) * CCH + scol;
    const unsigned short* Yg0 = Y  + (size_t)(pp0 + wid * 32 + srow) * CCH + scol;

#pragma unroll
    for (int qi = 0; qi < 2; ++qi) {
        gload16(Wg0 + (size_t)qi * 16 * CCH, &Wt[0][wid * 32 + qi * 16][0]);
        gload16(Yg0 + (size_t)qi * 16 * CCH, &Yt[0][wid * 32 + qi * 16][0]);
    }
    __syncthreads();

    for (int kt = 0; kt < 12; ++kt) {
        int cur = kt & 1;
        if (kt < 11) {
            int k1 = (kt + 1) * 32;
#pragma unroll
            for (int qi = 0; qi < 2; ++qi) {
                gload16(Wg0 + (size_t)qi * 16 * CCH + k1, &Wt[cur ^ 1][wid * 32 + qi * 16][0]);
                gload16(Yg0 + (size_t)qi * 16 * CCH + k1, &Yt[cur ^ 1][wid * 32 + qi * 16][0]);
            }
        }

        bh8 a[4], b[4];
#pragma unroll
        for (int mf = 0; mf < 4; ++mf)
            a[mf] = *(const bh8*)&A3[cur][wr * 64 + mf * 16 + li][gsw];
#pragma unroll
        for (int nf = 0; nf < 4; ++nf)
            b[nf] = *(const bh8*)&B3[cur][wc * 64 + nf * 16 + li][gsw];
#pragma unroll
        for (int mf = 0; mf < 4; ++mf)
#pragma unroll
            for (int nf = 0; nf < 4; ++nf)
                acc[mf][nf] = __builtin_amdgcn_mfma_f32_16x16x32_bf16(
                    a[mf], b[nf], acc[mf][nf], 0, 0, 0);

        __syncthreads();
    }

    if (!vmode) {
        // D rows = c (A=W), cols = p. T16[p_local][c_local]; out [p][c].
#pragma unroll
        for (int mf = 0; mf < 4; ++mf) {
            int cl = wr * 64 + mf * 16 + g * 4;
            float4 bv = *(const float4*)&bias[cm0 + cl];
#pragma unroll
            for (int nf = 0; nf < 4; ++nf) {
                int pl = wc * 64 + nf * 16 + li;
                us4 o;
                o[0] = f2bf((acc[mf][nf][0] + bv.x) * sc);
                o[1] = f2bf((acc[mf][nf][1] + bv.y) * sc);
                o[2] = f2bf((acc[mf][nf][2] + bv.z) * sc);
                o[3] = f2bf((acc[mf][nf][3] + bv.w) * sc);
                *(us4*)&T16[pl][cl] = o;
            }
        }
        __syncthreads();
#pragma unroll
        for (int it = 0; it < 8; ++it) {
            int row = it * 16 + wid * 4 + (lid >> 4);
            int col = (lid & 15) * 8;
            us8 vv = *(const us8*)&T16[row][col];
            *(us8*)(outb + (size_t)(pp0 + row) * CCH + cm0 + col) = vv;
        }
    } else {
        // D rows = p (A=Y), cols = c. T16[c_local][p_local]; out [n][c][p_l].
#pragma unroll
        for (int nf = 0; nf < 4; ++nf) {
            int cl = wc * 64 + nf * 16 + li;
            float bv = bias[cm0 + cl];
#pragma unroll
            for (int mf = 0; mf < 4; ++mf) {
                int pl = wr * 64 + mf * 16 + g * 4;
                us4 o;
                o[0] = f2bf(acc[mf][nf][0] + bv);
                o[1] = f2bf(acc[mf][nf][1] + bv);
                o[2] = f2bf(acc[mf][nf][2] + bv);
                o[3] = f2bf(acc[mf][nf][3] + bv);
                *(us4*)&T16[cl][pl] = o;
            }
        }
        __syncthreads();
        int n = pp0 / HWP;
        int pl0 = pp0 - n * HWP;
#pragma unroll
        for (int it = 0; it < 8; ++it) {
            int row = it * 16 + wid * 4 + (lid >> 4);   // c_local
            int col = (lid & 15) * 8;                   // p_local
            us8 vv = *(const us8*)&T16[row][col];
            *(us8*)(outb + (size_t)(n * CCH + cm0 + row) * HWP + pl0 + col) = vv;
        }
    }
}

// ---------------------------------------------------------------------------
// proj GEMM: 1-D grid 1728 = 8 x 216, c-tile innermost; LDS swizzle as above.
// fp32 std-layout output with inverse window gather (direct stores).
// ---------------------------------------------------------------------------
__global__ __launch_bounds__(256) void proj_gemm(
    const unsigned short* __restrict__ Y, const unsigned short* __restrict__ Wb,
    const float* __restrict__ bias, float* __restrict__ outf)
{
    __shared__ unsigned short Wt[2][128][32];
    __shared__ unsigned short Yt[2][128][32];

    int bL = blockIdx.x;
    int O  = (bL & 7) * 216 + (bL >> 3);
    int py = O / 3;
    int cx = O - py * 3;
    int pp0 = py * 128, cm0 = cx * 128;

    int tid = threadIdx.x;
    int lid = tid & 63, wid = tid >> 6;
    int wr = wid >> 1, wc = wid & 1;
    int li = lid & 15, g = lid >> 4;

    int srow = (lid >> 2);
    int scol = (((lid & 3) ^ ((srow >> 1) & 3))) * 8;
    int gsw = (g ^ ((li >> 1) & 3)) * 8;

    fx4 acc[4][4];
#pragma unroll
    for (int i = 0; i < 4; ++i)
#pragma unroll
        for (int j = 0; j < 4; ++j) acc[i][j] = (fx4){0.f, 0.f, 0.f, 0.f};

    const unsigned short* Wg0 = Wb + (size_t)(cm0 + wid * 32 + srow) * CCH + scol;
    const unsigned short* Yg0 = Y  + (size_t)(pp0 + wid * 32 + srow) * CCH + scol;

#pragma unroll
    for (int qi = 0; qi < 2; ++qi) {
        gload16(Wg0 + (size_t)qi * 16 * CCH, &Wt[0][wid * 32 + qi * 16][0]);
        gload16(Yg0 + (size_t)qi * 16 * CCH, &Yt[0][wid * 32 + qi * 16][0]);
    }
    __syncthreads();

    for (int kt = 0; kt < 12; ++kt) {
        int cur = kt & 1;
        if (kt < 11) {
            int k1 = (kt + 1) * 32;
#pragma unroll
            for (int qi = 0; qi < 2; ++qi) {
                gload16(Wg0 + (size_t)qi * 16 * CCH + k1, &Wt[cur ^ 1][wid * 32 + qi * 16][0]);
                gload16(Yg0 + (size_t)qi * 16 * CCH + k1, &Yt[cur ^ 1][wid * 32 + qi * 16][0]);
            }
        }

        bh8 a[4], b[4];
#pragma unroll
        for (int mf = 0; mf < 4; ++mf)
            a[mf] = *(const bh8*)&Wt[cur][wr * 64 + mf * 16 + li][gsw];
#pragma unroll
        for (int nf = 0; nf < 4; ++nf)
            b[nf] = *(const bh8*)&Yt[cur][wc * 64 + nf * 16 + li][gsw];
#pragma unroll
        for (int mf = 0; mf < 4; ++mf)
#pragma unroll
            for (int nf = 0; nf < 4; ++nf)
                acc[mf][nf] = __builtin_amdgcn_mfma_f32_16x16x32_bf16(
                    a[mf], b[nf], acc[mf][nf], 0, 0, 0);

        __syncthreads();
    }

    // D rows = c, cols = p (lane). fp32 std layout, un-gather windows.
#pragma unroll
    for (int mf = 0; mf < 4; ++mf) {
        int c = cm0 + wr * 64 + mf * 16 + g * 4;
#pragma unroll
        for (int nf = 0; nf < 4; ++nf) {
            int p = pp0 + wc * 64 + nf * 16 + li;
            int n = p / HWP;
            int rem = p - n * HWP;
            int win = rem >> 6, t = rem & 63;
            int h = (win / NWIN) * 8 + (t >> 3);
            int w = (win % NWIN) * 8 + (t & 7);
            float* op = outf + (size_t)n * CCH * HWP + (size_t)h * WWD + w;
#pragma unroll
            for (int r = 0; r < 4; ++r)
                op[(size_t)(c + r) * HWP] = acc[mf][nf][r] + bias[c + r];
        }
    }
}

// ---------------------------------------------------------------------------
// MFMA window attention. block = one window (64 tokens); 4 waves x 3 heads.
// q,k: bf16 [p_wg][384]; v: bf16 [n][c][p_local] (= V^T); out: bf16 [p_wg][384].
// bias from precomputed Bx[head][tk][tq] f32 (L2-resident); no barriers.
// ---------------------------------------------------------------------------
__global__ __launch_bounds__(256) void attn(
    const unsigned short* __restrict__ q, const unsigned short* __restrict__ k,
    const unsigned short* __restrict__ v, const float* __restrict__ Bx,
    unsigned short* __restrict__ o)
{
    __shared__ unsigned short Pl[4][64][72];

    int tid = threadIdx.x, lid = tid & 63, wid = tid >> 6;
    int wl = blockIdx.x;
    int n = wl / WINS, winl = wl - n * WINS;
    int li = lid & 15, g = lid >> 4;

    const fx4 z = (fx4){0.f, 0.f, 0.f, 0.f};

    for (int hq = wid; hq < HEADS; hq += 4) {
        const unsigned short* qp = q + (size_t)(wl * 64) * CCH + hq * HD + g * 8;
        const unsigned short* kp = k + (size_t)(wl * 64) * CCH + hq * HD + g * 8;
        bh8 aq[4], bk[4];
#pragma unroll
        for (int mf = 0; mf < 4; ++mf)
            aq[mf] = *(const bh8*)(qp + (size_t)(mf * 16 + li) * CCH);
#pragma unroll
        for (int nf = 0; nf < 4; ++nf)
            bk[nf] = *(const bh8*)(kp + (size_t)(nf * 16 + li) * CCH);

        fx4 s[4][4];
#pragma unroll
        for (int mf = 0; mf < 4; ++mf)
#pragma unroll
            for (int nf = 0; nf < 4; ++nf)
                s[mf][nf] = __builtin_amdgcn_mfma_f32_16x16x32_bf16(aq[mf], bk[nf], z, 0, 0, 0);

        // bias: vector loads from expanded table (tq = mf*16+g*4+r, tk = nf*16+li)
#pragma unroll
        for (int mf = 0; mf < 4; ++mf)
#pragma unroll
            for (int nf = 0; nf < 4; ++nf) {
                fx4 bv = *(const fx4*)&Bx[((size_t)hq * 64 + nf * 16 + li) * 64
                                          + mf * 16 + g * 4];
                s[mf][nf] += bv;
            }

        // softmax across tk (lane group of 16 shares a row set)
        float inv_[4][4];
#pragma unroll
        for (int mf = 0; mf < 4; ++mf)
#pragma unroll
            for (int r = 0; r < 4; ++r) {
                float m = s[mf][0][r];
#pragma unroll
                for (int nf = 1; nf < 4; ++nf) m = fmaxf(m, s[mf][nf][r]);
                m = fmaxf(m, __shfl_xor(m, 1));
                m = fmaxf(m, __shfl_xor(m, 2));
                m = fmaxf(m, __shfl_xor(m, 4));
                m = fmaxf(m, __shfl_xor(m, 8));
                float sum = 0.f;
#pragma unroll
                for (int nf = 0; nf < 4; ++nf) {
                    float e = __expf(s[mf][nf][r] - m);
                    s[mf][nf][r] = e;
                    sum += e;
                }
                sum += __shfl_xor(sum, 1);
                sum += __shfl_xor(sum, 2);
                sum += __shfl_xor(sum, 4);
                sum += __shfl_xor(sum, 8);
                inv_[mf][r] = 1.f / sum;
            }

        // P -> per-wave LDS, bf16, row-major [tq][tk]
#pragma unroll
        for (int mf = 0; mf < 4; ++mf)
#pragma unroll
            for (int nf = 0; nf < 4; ++nf)
#pragma unroll
                for (int r = 0; r < 4; ++r)
                    Pl[wid][mf * 16 + g * 4 + r][nf * 16 + li] =
                        f2bf(s[mf][nf][r] * inv_[mf][r]);

        // O^T = V^T x P^T : D[d][tq]
        fx4 o2[2][4];
#pragma unroll
        for (int m2 = 0; m2 < 2; ++m2)
#pragma unroll
            for (int nf = 0; nf < 4; ++nf) o2[m2][nf] = z;
#pragma unroll
        for (int ks = 0; ks < 2; ++ks) {
            bh8 av[2], bp[4];
#pragma unroll
            for (int m2 = 0; m2 < 2; ++m2)
                av[m2] = *(const bh8*)(v + (size_t)(n * CCH + hq * HD + m2 * 16 + li) * HWP
                                         + winl * 64 + ks * 32 + g * 8);
#pragma unroll
            for (int nf = 0; nf < 4; ++nf)
                bp[nf] = *(const bh8*)&Pl[wid][nf * 16 + li][ks * 32 + g * 8];
#pragma unroll
            for (int m2 = 0; m2 < 2; ++m2)
#pragma unroll
                for (int nf = 0; nf < 4; ++nf)
                    o2[m2][nf] = __builtin_amdgcn_mfma_f32_16x16x32_bf16(
                        av[m2], bp[nf], o2[m2][nf], 0, 0, 0);
        }
#pragma unroll
        for (int nf = 0; nf < 4; ++nf) {
            int tq = nf * 16 + li;
#pragma unroll
            for (int m2 = 0; m2 < 2; ++m2) {
                int d = hq * HD + m2 * 16 + g * 4;
                us4 ov;
                ov[0] = f2bf(o2[m2][nf][0]);
                ov[1] = f2bf(o2[m2][nf][1]);
                ov[2] = f2bf(o2[m2][nf][2]);
                ov[3] = f2bf(o2[m2][nf][3]);
                *(us4*)(o + (size_t)(wl * 64 + tq) * CCH + d) = ov;
            }
        }
    }
}

// ---------------------------------------------------------------------------
extern "C" void kernel_launch(void* const* d_in, const int* in_sizes, int n_in,
                              void* d_out, int out_size, void* d_ws, size_t ws_size,
                              hipStream_t stream) {
    const float* vid  = (const float*)d_in[0];
    const float* qd_w = (const float*)d_in[1];
    const float* qd_b = (const float*)d_in[2];
    const float* qp_w = (const float*)d_in[3];
    const float* qp_b = (const float*)d_in[4];
    const float* kd_w = (const float*)d_in[5];
    const float* kd_b = (const float*)d_in[6];
    const float* kp_w = (const float*)d_in[7];
    const float* kp_b = (const float*)d_in[8];
    const float* vd_w = (const float*)d_in[9];
    const float* vd_b = (const float*)d_in[10];
    const float* vp_w = (const float*)d_in[11];
    const float* vp_b = (const float*)d_in[12];
    const float* rpb  = (const float*)d_in[13];
    const float* pj_w = (const float*)d_in[14];
    const float* pj_b = (const float*)d_in[15];

    unsigned short* ws16 = (unsigned short*)d_ws;
    unsigned short* tr0 = ws16 + 3 * EELEM;     // [p_wg][c] bf16 (q,k,v pre-GEMM)
    unsigned short* tr1 = ws16 + 4 * EELEM;
    unsigned short* tr2 = ws16 + 5 * EELEM;
    unsigned short* Wb  = ws16 + 6 * EELEM;     // 4 x 147456 bf16
    float* dwT          = (float*)(Wb + 4 * WMAT);      // [3][9][384] fp32
    float* Bx           = dwT + 3 * 9 * CCH;            // [12][64][64] fp32
    unsigned short* qb  = ws16;                 // post-GEMM q,k,v
    unsigned short* kb  = ws16 + EELEM;
    unsigned short* vb  = ws16 + 2 * EELEM;
    unsigned short* ob  = tr0;                  // attn out reuses tr region

    prep<<<521, 256, 0, stream>>>(qp_w, kp_w, vp_w, pj_w,
                                  qd_w, kd_w, vd_w, rpb, Wb, dwT, Bx);
    dwgather<<<NIMG * WINS * 6, 256, 0, stream>>>(
        vid, dwT, qd_b, kd_b, vd_b, tr0, tr1, tr2);

    const float scale = 0.17677669529663687f;   // 32^-0.5 folded into q
    qkv_gemm<<<5184, 256, 0, stream>>>(
        tr0, tr1, tr2, Wb, qp_b, kp_b, vp_b, scale, qb, kb, vb);

    attn<<<NIMG * WINS, 256, 0, stream>>>(qb, kb, vb, Bx, ob);

    proj_gemm<<<1728, 256, 0, stream>>>(
        ob, Wb + 3 * WMAT, pj_b, (float*)d_out);
}

// Round 14
// 373.373 us; speedup vs baseline: 1.1265x; 1.0584x over previous
//
#include <hip/hip_runtime.h>

#define CCH 384
#define HH 192
#define WWD 192
#define NIMG 2
#define HWP (HH * WWD)        // 36864 pixels per image
#define PTOT (NIMG * HWP)     // 73728
#define HEADS 12
#define HD 32
#define NWIN 24
#define WINS 576              // windows per image
#define EELEM ((size_t)NIMG * CCH * HWP)   // elems per tensor (28,311,552)
#define WMAT 147456           // 384*384

typedef __attribute__((ext_vector_type(8))) short bh8;            // 8 bf16 (MFMA frag)
typedef __attribute__((ext_vector_type(8))) unsigned short us8;
typedef __attribute__((ext_vector_type(4))) unsigned short us4;
typedef __attribute__((ext_vector_type(4))) float fx4;

__device__ __forceinline__ unsigned short f2bf(float f) {
    unsigned u = __float_as_uint(f);
    u += 0x7fffu + ((u >> 16) & 1u);      // round-to-nearest-even
    return (unsigned short)(u >> 16);
}

__device__ __forceinline__ void gload16(const void* g, void* l) {
    __builtin_amdgcn_global_load_lds(
        (const __attribute__((address_space(1))) void*)g,
        (__attribute__((address_space(3))) void*)l, 16, 0, 0);
}

// ---------------------------------------------------------------------------
// prep (merged): [0,288) pw weights->bf16; [288,329) dw weight transpose;
// [329,521) rel-pos bias expansion Bx[head][tk][tq].
// ---------------------------------------------------------------------------
__global__ __launch_bounds__(256) void prep(
    const float* __restrict__ qp, const float* __restrict__ kp,
    const float* __restrict__ vp, const float* __restrict__ pj,
    const float* __restrict__ qd, const float* __restrict__ kd,
    const float* __restrict__ vd, const float* __restrict__ rpb,
    unsigned short* __restrict__ Wb, float* __restrict__ dwT,
    float* __restrict__ Bx)
{
    int bx = blockIdx.x;
    if (bx < 288) {
        int idx8 = (bx * 256 + threadIdx.x) * 8;
        int which = idx8 / WMAT;
        int loc = idx8 - which * WMAT;
        const float* s = (which == 0) ? qp : (which == 1) ? kp : (which == 2) ? vp : pj;
        float4 v0 = *(const float4*)(s + loc);
        float4 v1 = *(const float4*)(s + loc + 4);
        us8 ov;
        ov[0] = f2bf(v0.x); ov[1] = f2bf(v0.y); ov[2] = f2bf(v0.z); ov[3] = f2bf(v0.w);
        ov[4] = f2bf(v1.x); ov[5] = f2bf(v1.y); ov[6] = f2bf(v1.z); ov[7] = f2bf(v1.w);
        *(us8*)(Wb + idx8) = ov;
    } else if (bx < 329) {
        int idx = (bx - 288) * 256 + threadIdx.x;
        if (idx < 3 * 9 * CCH) {
            int ten = idx / (9 * CCH);
            int rem = idx - ten * (9 * CCH);
            int tap = rem / CCH;
            int c   = rem - tap * CCH;
            const float* s = (ten == 0) ? qd : (ten == 1) ? kd : vd;
            dwT[idx] = s[c * 9 + tap];
        }
    } else {
        int idx = (bx - 329) * 256 + threadIdx.x;   // 192*256 = 49152 exact
        int h  = idx >> 12;
        int tk = (idx >> 6) & 63;
        int tq = idx & 63;
        int dy = (tq >> 3) - (tk >> 3) + 7;
        int dx = (tq & 7) - (tk & 7) + 7;
        Bx[idx] = rpb[(dy * 15 + dx) * HEADS + h];
    }
}

// ---------------------------------------------------------------------------
// FUSED depthwise 3x3 + bias + window-gather transpose (v7, proven 125us).
// ---------------------------------------------------------------------------
__global__ __launch_bounds__(256) void dwgather(
    const float* __restrict__ x,
    const float* __restrict__ wt,       // [3][9][384] fp32 transposed dw weights
    const float* __restrict__ qb, const float* __restrict__ kb,
    const float* __restrict__ vb,
    unsigned short* __restrict__ oq, unsigned short* __restrict__ ok,
    unsigned short* __restrict__ ov)
{
    __shared__ float halo[64 * 121];        // 30.25 KB

    // bijective XCD swizzle: 6912 = 8 * 864
    int bid = blockIdx.x;
    int b = (bid & 7) * 864 + (bid >> 3);
    int wtx  = b % 24;
    int strip = b / 24;                     // 0..287
    int chv  = strip % 6;
    int nwy  = strip / 6;                   // 0..47
    int wy   = nwy % 24;
    int n    = nwy / 24;

    int h0 = wy * 8, w0 = wtx * 8;
    int tid = threadIdx.x;
    int c   = tid & 63;                     // channel within chunk (lane-varying)
    int pxg = tid >> 6;                     // wave id: owns pixel rows 2pxg,2pxg+1
    int cg  = chv * 64 + c;
    int widx = n * WINS + wy * NWIN + wtx;

    const float* xbase = x + (size_t)n * CCH * HWP + (size_t)(chv * 64) * HWP;

    // ---- stage halo: 64ch x 10 rows x 12 cols (cols w0-2 .. w0+9) ----
    for (int j = tid; j < 1920; j += 256) {
        int seg = j % 3;
        int t   = j / 3;
        int rr  = t % 10;
        int cc  = t / 10;
        int hr  = h0 - 1 + rr;
        int cb  = w0 - 2 + seg * 4;
        float4 val = make_float4(0.f, 0.f, 0.f, 0.f);
        if (hr >= 0 && hr < HH) {
            const float* p = xbase + (size_t)cc * HWP + (size_t)hr * WWD;
            if (cb >= 0 && cb + 4 <= WWD) {
                val = *(const float4*)(p + cb);
            } else {
                if (cb + 0 >= 0 && cb + 0 < WWD) val.x = p[cb + 0];
                if (cb + 1 >= 0 && cb + 1 < WWD) val.y = p[cb + 1];
                if (cb + 2 >= 0 && cb + 2 < WWD) val.z = p[cb + 2];
                if (cb + 3 >= 0 && cb + 3 < WWD) val.w = p[cb + 3];
            }
        }
        int hb = cc * 121 + rr * 12 + seg * 4;
        halo[hb + 0] = val.x;
        halo[hb + 1] = val.y;
        halo[hb + 2] = val.z;
        halo[hb + 3] = val.w;
    }

    // ---- per-lane weights, coalesced ([tap][384] layout) ----
    float wq[9], wk[9], wv[9];
#pragma unroll
    for (int t = 0; t < 9; ++t) {
        wq[t] = wt[t * CCH + cg];
        wk[t] = wt[9 * CCH + t * CCH + cg];
        wv[t] = wt[18 * CCH + t * CCH + cg];
    }
    float bqv = qb[cg], bkv = kb[cg], bvv = vb[cg];

    __syncthreads();

    // ---- register sliding window: rows 2pxg..2pxg+3, cols 1..10 ----
    const int hbase = c * 121 + (2 * pxg) * 12;
    float r0[10], r1[10], r2[10];
#pragma unroll
    for (int cc = 0; cc < 10; ++cc) r0[cc] = halo[hbase + cc + 1];
#pragma unroll
    for (int cc = 0; cc < 10; ++cc) r1[cc] = halo[hbase + 12 + cc + 1];
#pragma unroll
    for (int cc = 0; cc < 10; ++cc) r2[cc] = halo[hbase + 24 + cc + 1];

    size_t ob0 = ((size_t)widx * 64 + pxg * 16) * CCH + cg;

    // pixel row 0: taps r0,r1,r2
#pragma unroll
    for (int pc = 0; pc < 8; ++pc) {
        float sq = 0.f, sk = 0.f, sv = 0.f;
#pragma unroll
        for (int dc = 0; dc < 3; ++dc) {
            float x0 = r0[pc + dc], x1 = r1[pc + dc], x2 = r2[pc + dc];
            sq = fmaf(x0, wq[dc], sq);     sk = fmaf(x0, wk[dc], sk);     sv = fmaf(x0, wv[dc], sv);
            sq = fmaf(x1, wq[3 + dc], sq); sk = fmaf(x1, wk[3 + dc], sk); sv = fmaf(x1, wv[3 + dc], sv);
            sq = fmaf(x2, wq[6 + dc], sq); sk = fmaf(x2, wk[6 + dc], sk); sv = fmaf(x2, wv[6 + dc], sv);
        }
        size_t o = ob0 + (size_t)pc * CCH;
        oq[o] = f2bf(sq + bqv);
        ok[o] = f2bf(sk + bkv);
        ov[o] = f2bf(sv + bvv);
    }

    // rotate: r0 <- row 2pxg+3
#pragma unroll
    for (int cc = 0; cc < 10; ++cc) r0[cc] = halo[hbase + 36 + cc + 1];

    // pixel row 1: taps r1,r2,r0
#pragma unroll
    for (int pc = 0; pc < 8; ++pc) {
        float sq = 0.f, sk = 0.f, sv = 0.f;
#pragma unroll
        for (int dc = 0; dc < 3; ++dc) {
            float x0 = r1[pc + dc], x1 = r2[pc + dc], x2 = r0[pc + dc];
            sq = fmaf(x0, wq[dc], sq);     sk = fmaf(x0, wk[dc], sk);     sv = fmaf(x0, wv[dc], sv);
            sq = fmaf(x1, wq[3 + dc], sq); sk = fmaf(x1, wk[3 + dc], sk); sv = fmaf(x1, wv[3 + dc], sv);
            sq = fmaf(x2, wq[6 + dc], sq); sk = fmaf(x2, wk[6 + dc], sk); sv = fmaf(x2, wv[6 + dc], sv);
        }
        size_t o = ob0 + (size_t)(8 + pc) * CCH;
        oq[o] = f2bf(sq + bqv);
        ok[o] = f2bf(sk + bkv);
        ov[o] = f2bf(sv + bvv);
    }
}

// issue macro shared by both GEMMs: one K-tile (4 gload16 per wave)
#define ISSUE_TILE(KT, BUF)                                                     \
    do {                                                                        \
        int k0_ = (KT) * 32;                                                    \
        gload16(Wg0 + k0_,                     &Wt[BUF][wid * 32][0]);          \
        gload16(Wg0 + (size_t)16 * CCH + k0_,  &Wt[BUF][wid * 32 + 16][0]);     \
        gload16(Yg0 + k0_,                     &Yt[BUF][wid * 32][0]);          \
        gload16(Yg0 + (size_t)16 * CCH + k0_,  &Yt[BUF][wid * 32 + 16][0]);     \
    } while (0)

// ---------------------------------------------------------------------------
// MERGED q/k/v bf16 MFMA GEMM, depth-2 counted-vmcnt pipeline (T4).
// FIX vs R13: bias preloaded to registers + vmcnt(0) drain BEFORE the
// prologue, so the in-loop vmcnt ledger contains ONLY the 4-per-tile
// gload_lds (compiler-hoisted bias loads were corrupting the counts).
// 3 LDS buffers; per step: vmcnt(4) -> raw barrier -> issue T+2 -> MFMA.
// 1-D grid 5184 = 8 XCD x 648, c-tile innermost (Y panel L2 reuse).
// LDS st-swizzle both sides. z=0: q (*scale), z=1: k, z=2: v (V^T out).
// ---------------------------------------------------------------------------
__global__ __launch_bounds__(256) void qkv_gemm(
    const unsigned short* __restrict__ tr0, const unsigned short* __restrict__ tr1,
    const unsigned short* __restrict__ tr2, const unsigned short* __restrict__ Wball,
    const float* __restrict__ qpb, const float* __restrict__ kpb,
    const float* __restrict__ vpb, float scale,
    unsigned short* __restrict__ qo, unsigned short* __restrict__ ko,
    unsigned short* __restrict__ vo)
{
    __shared__ __align__(16) char smem[49152];   // staging [3] bufs U epilogue T16
    typedef unsigned short (*tile3)[128][32];
    tile3 Wt = (tile3)smem;                      // [3][128][32]
    tile3 Yt = (tile3)(smem + 24576);
    typedef unsigned short (*tep_t)[132];
    tep_t T16 = (tep_t)smem;

    // decode: O = tensor-major, then p-tile, c-tile innermost (L2 reuse of Y)
    int bL = blockIdx.x;
    int O  = (bL & 7) * 648 + (bL >> 3);
    int z  = O / 1728;
    int rem = O - z * 1728;
    int py = rem / 3;
    int cx = rem - py * 3;
    int pp0 = py * 128, cm0 = cx * 128;

    const unsigned short* Y  = (z == 0) ? tr0 : (z == 1) ? tr1 : tr2;
    const unsigned short* Wb = Wball + (size_t)z * WMAT;
    const float* bias        = (z == 0) ? qpb : (z == 1) ? kpb : vpb;
    float sc                 = (z == 0) ? scale : 1.0f;
    unsigned short* outb     = (z == 0) ? qo : (z == 1) ? ko : vo;
    bool vmode = (z == 2);

    int tid = threadIdx.x;
    int lid = tid & 63, wid = tid >> 6;
    int wr = wid >> 1, wc = wid & 1;
    int li = lid & 15, g = lid >> 4;

    // staging: srow 0..15 in 16-row group; SOURCE slot pre-swizzled
    int srow = (lid >> 2);
    int scol = (((lid & 3) ^ ((srow >> 1) & 3))) * 8;
    // read-side swizzled k-slot (row base multiples of 16 -> depends on li only)
    int gsw = (g ^ ((li >> 1) & 3)) * 8;

    fx4 acc[4][4];
#pragma unroll
    for (int i = 0; i < 4; ++i)
#pragma unroll
        for (int j = 0; j < 4; ++j) acc[i][j] = (fx4){0.f, 0.f, 0.f, 0.f};

    tile3 A3 = vmode ? Yt : Wt;          // block-uniform select
    tile3 B3 = vmode ? Wt : Yt;

    const unsigned short* Wg0 = Wb + (size_t)(cm0 + wid * 32 + srow) * CCH + scol;
    const unsigned short* Yg0 = Y  + (size_t)(pp0 + wid * 32 + srow) * CCH + scol;

    // ---- preload epilogue bias to registers, DRAIN, so loop vmcnt is exact --
    float4 bv4[4];
    float  bvs[4];
    if (!vmode) {
#pragma unroll
        for (int mf = 0; mf < 4; ++mf)
            bv4[mf] = *(const float4*)&bias[cm0 + wr * 64 + mf * 16 + g * 4];
    } else {
#pragma unroll
        for (int nf = 0; nf < 4; ++nf)
            bvs[nf] = bias[cm0 + wc * 64 + nf * 16 + li];
    }
    asm volatile("s_waitcnt vmcnt(0)" ::: "memory");
    __builtin_amdgcn_sched_barrier(0);

    ISSUE_TILE(0, 0);
    ISSUE_TILE(1, 1);

#pragma unroll
    for (int kt = 0; kt < 12; ++kt) {
        __builtin_amdgcn_sched_barrier(0);
        if (kt < 11) asm volatile("s_waitcnt vmcnt(4)" ::: "memory");
        else         asm volatile("s_waitcnt vmcnt(0)" ::: "memory");
        __builtin_amdgcn_s_barrier();            // raw: no implicit drain
        __builtin_amdgcn_sched_barrier(0);
        if (kt < 10) ISSUE_TILE(kt + 2, (kt + 2) % 3);

        int cur = kt % 3;
        bh8 a[4], b[4];
#pragma unroll
        for (int mf = 0; mf < 4; ++mf)
            a[mf] = *(const bh8*)&A3[cur][wr * 64 + mf * 16 + li][gsw];
#pragma unroll
        for (int nf = 0; nf < 4; ++nf)
            b[nf] = *(const bh8*)&B3[cur][wc * 64 + nf * 16 + li][gsw];
#pragma unroll
        for (int mf = 0; mf < 4; ++mf)
#pragma unroll
            for (int nf = 0; nf < 4; ++nf)
                acc[mf][nf] = __builtin_amdgcn_mfma_f32_16x16x32_bf16(
                    a[mf], b[nf], acc[mf][nf], 0, 0, 0);
    }

    __syncthreads();                     // staging dead; safe to overwrite w/ T16

    if (!vmode) {
        // D rows = c (A=W), cols = p. T16[p_local][c_local]; out [p][c].
#pragma unroll
        for (int mf = 0; mf < 4; ++mf) {
            int cl = wr * 64 + mf * 16 + g * 4;
            float4 bv = bv4[mf];
#pragma unroll
            for (int nf = 0; nf < 4; ++nf) {
                int pl = wc * 64 + nf * 16 + li;
                us4 o;
                o[0] = f2bf((acc[mf][nf][0] + bv.x) * sc);
                o[1] = f2bf((acc[mf][nf][1] + bv.y) * sc);
                o[2] = f2bf((acc[mf][nf][2] + bv.z) * sc);
                o[3] = f2bf((acc[mf][nf][3] + bv.w) * sc);
                *(us4*)&T16[pl][cl] = o;
            }
        }
        __syncthreads();
#pragma unroll
        for (int it = 0; it < 8; ++it) {
            int row = it * 16 + wid * 4 + (lid >> 4);
            int col = (lid & 15) * 8;
            us8 vv = *(const us8*)&T16[row][col];
            *(us8*)(outb + (size_t)(pp0 + row) * CCH + cm0 + col) = vv;
        }
    } else {
        // D rows = p (A=Y), cols = c. T16[c_local][p_local]; out [n][c][p_l].
#pragma unroll
        for (int nf = 0; nf < 4; ++nf) {
            int cl = wc * 64 + nf * 16 + li;
            float bv = bvs[nf];
#pragma unroll
            for (int mf = 0; mf < 4; ++mf) {
                int pl = wr * 64 + mf * 16 + g * 4;
                us4 o;
                o[0] = f2bf(acc[mf][nf][0] + bv);
                o[1] = f2bf(acc[mf][nf][1] + bv);
                o[2] = f2bf(acc[mf][nf][2] + bv);
                o[3] = f2bf(acc[mf][nf][3] + bv);
                *(us4*)&T16[cl][pl] = o;
            }
        }
        __syncthreads();
        int n = pp0 / HWP;
        int pl0 = pp0 - n * HWP;
#pragma unroll
        for (int it = 0; it < 8; ++it) {
            int row = it * 16 + wid * 4 + (lid >> 4);   // c_local
            int col = (lid & 15) * 8;                   // p_local
            us8 vv = *(const us8*)&T16[row][col];
            *(us8*)(outb + (size_t)(n * CCH + cm0 + row) * HWP + pl0 + col) = vv;
        }
    }
}

// ---------------------------------------------------------------------------
// proj GEMM: same depth-2 counted-vmcnt pipeline with preloaded+drained bias;
// direct fp32 scatter stores. 1-D grid 1728 = 8 x 216, c-tile innermost.
// ---------------------------------------------------------------------------
__global__ __launch_bounds__(256) void proj_gemm(
    const unsigned short* __restrict__ Y, const unsigned short* __restrict__ Wb,
    const float* __restrict__ bias, float* __restrict__ outf)
{
    __shared__ unsigned short Wt[3][128][32];
    __shared__ unsigned short Yt[3][128][32];

    int bL = blockIdx.x;
    int O  = (bL & 7) * 216 + (bL >> 3);
    int py = O / 3;
    int cx = O - py * 3;
    int pp0 = py * 128, cm0 = cx * 128;

    int tid = threadIdx.x;
    int lid = tid & 63, wid = tid >> 6;
    int wr = wid >> 1, wc = wid & 1;
    int li = lid & 15, g = lid >> 4;

    int srow = (lid >> 2);
    int scol = (((lid & 3) ^ ((srow >> 1) & 3))) * 8;
    int gsw = (g ^ ((li >> 1) & 3)) * 8;

    fx4 acc[4][4];
#pragma unroll
    for (int i = 0; i < 4; ++i)
#pragma unroll
        for (int j = 0; j < 4; ++j) acc[i][j] = (fx4){0.f, 0.f, 0.f, 0.f};

    const unsigned short* Wg0 = Wb + (size_t)(cm0 + wid * 32 + srow) * CCH + scol;
    const unsigned short* Yg0 = Y  + (size_t)(pp0 + wid * 32 + srow) * CCH + scol;

    // preload bias (float4 per mf), drain so loop vmcnt ledger is exact
    float4 bv4[4];
#pragma unroll
    for (int mf = 0; mf < 4; ++mf)
        bv4[mf] = *(const float4*)&bias[cm0 + wr * 64 + mf * 16 + g * 4];
    asm volatile("s_waitcnt vmcnt(0)" ::: "memory");
    __builtin_amdgcn_sched_barrier(0);

    ISSUE_TILE(0, 0);
    ISSUE_TILE(1, 1);

#pragma unroll
    for (int kt = 0; kt < 12; ++kt) {
        __builtin_amdgcn_sched_barrier(0);
        if (kt < 11) asm volatile("s_waitcnt vmcnt(4)" ::: "memory");
        else         asm volatile("s_waitcnt vmcnt(0)" ::: "memory");
        __builtin_amdgcn_s_barrier();
        __builtin_amdgcn_sched_barrier(0);
        if (kt < 10) ISSUE_TILE(kt + 2, (kt + 2) % 3);

        int cur = kt % 3;
        bh8 a[4], b[4];
#pragma unroll
        for (int mf = 0; mf < 4; ++mf)
            a[mf] = *(const bh8*)&Wt[cur][wr * 64 + mf * 16 + li][gsw];
#pragma unroll
        for (int nf = 0; nf < 4; ++nf)
            b[nf] = *(const bh8*)&Yt[cur][wc * 64 + nf * 16 + li][gsw];
#pragma unroll
        for (int mf = 0; mf < 4; ++mf)
#pragma unroll
            for (int nf = 0; nf < 4; ++nf)
                acc[mf][nf] = __builtin_amdgcn_mfma_f32_16x16x32_bf16(
                    a[mf], b[nf], acc[mf][nf], 0, 0, 0);
    }

    // D rows = c, cols = p (lane). fp32 std layout, un-gather windows.
#pragma unroll
    for (int mf = 0; mf < 4; ++mf) {
        int c = cm0 + wr * 64 + mf * 16 + g * 4;
#pragma unroll
        for (int nf = 0; nf < 4; ++nf) {
            int p = pp0 + wc * 64 + nf * 16 + li;
            int n = p / HWP;
            int rem = p - n * HWP;
            int win = rem >> 6, t = rem & 63;
            int h = (win / NWIN) * 8 + (t >> 3);
            int w = (win % NWIN) * 8 + (t & 7);
            float* op = outf + (size_t)n * CCH * HWP + (size_t)h * WWD + w;
            op[(size_t)(c + 0) * HWP] = acc[mf][nf][0] + bv4[mf].x;
            op[(size_t)(c + 1) * HWP] = acc[mf][nf][1] + bv4[mf].y;
            op[(size_t)(c + 2) * HWP] = acc[mf][nf][2] + bv4[mf].z;
            op[(size_t)(c + 3) * HWP] = acc[mf][nf][3] + bv4[mf].w;
        }
    }
}

// ---------------------------------------------------------------------------
// MFMA window attention. block = one window (64 tokens); 4 waves x 3 heads.
// q,k: bf16 [p_wg][384]; v: bf16 [n][c][p_local] (= V^T); out: bf16 [p_wg][384].
// bias from precomputed Bx[head][tk][tq] f32 (L2-resident); no barriers.
// ---------------------------------------------------------------------------
__global__ __launch_bounds__(256) void attn(
    const unsigned short* __restrict__ q, const unsigned short* __restrict__ k,
    const unsigned short* __restrict__ v, const float* __restrict__ Bx,
    unsigned short* __restrict__ o)
{
    __shared__ unsigned short Pl[4][64][72];

    int tid = threadIdx.x, lid = tid & 63, wid = tid >> 6;
    int wl = blockIdx.x;
    int n = wl / WINS, winl = wl - n * WINS;
    int li = lid & 15, g = lid >> 4;

    const fx4 z = (fx4){0.f, 0.f, 0.f, 0.f};

    for (int hq = wid; hq < HEADS; hq += 4) {
        const unsigned short* qp = q + (size_t)(wl * 64) * CCH + hq * HD + g * 8;
        const unsigned short* kp = k + (size_t)(wl * 64) * CCH + hq * HD + g * 8;
        bh8 aq[4], bk[4];
#pragma unroll
        for (int mf = 0; mf < 4; ++mf)
            aq[mf] = *(const bh8*)(qp + (size_t)(mf * 16 + li) * CCH);
#pragma unroll
        for (int nf = 0; nf < 4; ++nf)
            bk[nf] = *(const bh8*)(kp + (size_t)(nf * 16 + li) * CCH);

        fx4 s[4][4];
#pragma unroll
        for (int mf = 0; mf < 4; ++mf)
#pragma unroll
            for (int nf = 0; nf < 4; ++nf)
                s[mf][nf] = __builtin_amdgcn_mfma_f32_16x16x32_bf16(aq[mf], bk[nf], z, 0, 0, 0);

        // bias: vector loads from expanded table (tq = mf*16+g*4+r, tk = nf*16+li)
#pragma unroll
        for (int mf = 0; mf < 4; ++mf)
#pragma unroll
            for (int nf = 0; nf < 4; ++nf) {
                fx4 bv = *(const fx4*)&Bx[((size_t)hq * 64 + nf * 16 + li) * 64
                                          + mf * 16 + g * 4];
                s[mf][nf] += bv;
            }

        // softmax across tk (lane group of 16 shares a row set)
        float inv_[4][4];
#pragma unroll
        for (int mf = 0; mf < 4; ++mf)
#pragma unroll
            for (int r = 0; r < 4; ++r) {
                float m = s[mf][0][r];
#pragma unroll
                for (int nf = 1; nf < 4; ++nf) m = fmaxf(m, s[mf][nf][r]);
                m = fmaxf(m, __shfl_xor(m, 1));
                m = fmaxf(m, __shfl_xor(m, 2));
                m = fmaxf(m, __shfl_xor(m, 4));
                m = fmaxf(m, __shfl_xor(m, 8));
                float sum = 0.f;
#pragma unroll
                for (int nf = 0; nf < 4; ++nf) {
                    float e = __expf(s[mf][nf][r] - m);
                    s[mf][nf][r] = e;
                    sum += e;
                }
                sum += __shfl_xor(sum, 1);
                sum += __shfl_xor(sum, 2);
                sum += __shfl_xor(sum, 4);
                sum += __shfl_xor(sum, 8);
                inv_[mf][r] = 1.f / sum;
            }

        // P -> per-wave LDS, bf16, row-major [tq][tk]
#pragma unroll
        for (int mf = 0; mf < 4; ++mf)
#pragma unroll
            for (int nf = 0; nf < 4; ++nf)
#pragma unroll
                for (int r = 0; r < 4; ++r)
                    Pl[wid][mf * 16 + g * 4 + r][nf * 16 + li] =
                        f2bf(s[mf][nf][r] * inv_[mf][r]);

        // O^T = V^T x P^T : D[d][tq]
        fx4 o2[2][4];
#pragma unroll
        for (int m2 = 0; m2 < 2; ++m2)
#pragma unroll
            for (int nf = 0; nf < 4; ++nf) o2[m2][nf] = z;
#pragma unroll
        for (int ks = 0; ks < 2; ++ks) {
            bh8 av[2], bp[4];
#pragma unroll
            for (int m2 = 0; m2 < 2; ++m2)
                av[m2] = *(const bh8*)(v + (size_t)(n * CCH + hq * HD + m2 * 16 + li) * HWP
                                         + winl * 64 + ks * 32 + g * 8);
#pragma unroll
            for (int nf = 0; nf < 4; ++nf)
                bp[nf] = *(const bh8*)&Pl[wid][nf * 16 + li][ks * 32 + g * 8];
#pragma unroll
            for (int m2 = 0; m2 < 2; ++m2)
#pragma unroll
                for (int nf = 0; nf < 4; ++nf)
                    o2[m2][nf] = __builtin_amdgcn_mfma_f32_16x16x32_bf16(
                        av[m2], bp[nf], o2[m2][nf], 0, 0, 0);
        }
#pragma unroll
        for (int nf = 0; nf < 4; ++nf) {
            int tq = nf * 16 + li;
#pragma unroll
            for (int m2 = 0; m2 < 2; ++m2) {
                int d = hq * HD + m2 * 16 + g * 4;
                us4 ov;
                ov[0] = f2bf(o2[m2][nf][0]);
                ov[1] = f2bf(o2[m2][nf][1]);
                ov[2] = f2bf(o2[m2][nf][2]);
                ov[3] = f2bf(o2[m2][nf][3]);
                *(us4*)(o + (size_t)(wl * 64 + tq) * CCH + d) = ov;
            }
        }
    }
}

// ---------------------------------------------------------------------------
extern "C" void kernel_launch(void* const* d_in, const int* in_sizes, int n_in,
                              void* d_out, int out_size, void* d_ws, size_t ws_size,
                              hipStream_t stream) {
    const float* vid  = (const float*)d_in[0];
    const float* qd_w = (const float*)d_in[1];
    const float* qd_b = (const float*)d_in[2];
    const float* qp_w = (const float*)d_in[3];
    const float* qp_b = (const float*)d_in[4];
    const float* kd_w = (const float*)d_in[5];
    const float* kd_b = (const float*)d_in[6];
    const float* kp_w = (const float*)d_in[7];
    const float* kp_b = (const float*)d_in[8];
    const float* vd_w = (const float*)d_in[9];
    const float* vd_b = (const float*)d_in[10];
    const float* vp_w = (const float*)d_in[11];
    const float* vp_b = (const float*)d_in[12];
    const float* rpb  = (const float*)d_in[13];
    const float* pj_w = (const float*)d_in[14];
    const float* pj_b = (const float*)d_in[15];

    unsigned short* ws16 = (unsigned short*)d_ws;
    unsigned short* tr0 = ws16 + 3 * EELEM;     // [p_wg][c] bf16 (q,k,v pre-GEMM)
    unsigned short* tr1 = ws16 + 4 * EELEM;
    unsigned short* tr2 = ws16 + 5 * EELEM;
    unsigned short* Wb  = ws16 + 6 * EELEM;     // 4 x 147456 bf16
    float* dwT          = (float*)(Wb + 4 * WMAT);      // [3][9][384] fp32
    float* Bx           = dwT + 3 * 9 * CCH;            // [12][64][64] fp32
    unsigned short* qb  = ws16;                 // post-GEMM q,k,v
    unsigned short* kb  = ws16 + EELEM;
    unsigned short* vb  = ws16 + 2 * EELEM;
    unsigned short* ob  = tr0;                  // attn out reuses tr region

    prep<<<521, 256, 0, stream>>>(qp_w, kp_w, vp_w, pj_w,
                                  qd_w, kd_w, vd_w, rpb, Wb, dwT, Bx);
    dwgather<<<NIMG * WINS * 6, 256, 0, stream>>>(
        vid, dwT, qd_b, kd_b, vd_b, tr0, tr1, tr2);

    const float scale = 0.17677669529663687f;   // 32^-0.5 folded into q
    qkv_gemm<<<5184, 256, 0, stream>>>(
        tr0, tr1, tr2, Wb, qp_b, kp_b, vp_b, scale, qb, kb, vb);

    attn<<<NIMG * WINS, 256, 0, stream>>>(qb, kb, vb, Bx, ob);

    proj_gemm<<<1728, 256, 0, stream>>>(
        ob, Wb + 3 * WMAT, pj_b, (float*)d_out);
}